// Round 13
// baseline (170.434 us; speedup 1.0000x reference)
//
#include <hip/hip_runtime.h>

typedef float f32x4 __attribute__((ext_vector_type(4)));
typedef __bf16 bf16x8 __attribute__((ext_vector_type(8)));
typedef __bf16 bf16x4 __attribute__((ext_vector_type(4)));

#define H_DIM 4096
#define I_DIM 11008
#define BK 128                    // down-kernel k floats per step
#define KSTEPS_DN (I_DIM / BK)    // 86

// 2:4 prune of one contiguous group of 4 (stable argsort tie semantics).
// FLOAT-COMPARE version (passed R1-R5/R9-R12). Integer-key variant is
// empirically broken on this platform -- do not resurrect.
__device__ __forceinline__ f32x4 prune4(f32x4 w) {
    float a0 = fabsf(w[0]), a1 = fabsf(w[1]), a2 = fabsf(w[2]), a3 = fabsf(w[3]);
    int r0 = (int)(a1 < a0) + (int)(a2 < a0) + (int)(a3 < a0);
    int r1 = (int)(a0 <= a1) + (int)(a2 < a1) + (int)(a3 < a1);
    int r2 = (int)(a0 <= a2) + (int)(a1 <= a2) + (int)(a3 < a2);
    int r3 = (int)(a0 <= a3) + (int)(a1 <= a3) + (int)(a2 <= a3);
    w[0] = (r0 >= 2) ? w[0] : 0.0f;
    w[1] = (r1 >= 2) ? w[1] : 0.0f;
    w[2] = (r2 >= 2) ? w[2] : 0.0f;
    w[3] = (r3 >= 2) ? w[3] : 0.0f;
    return w;
}

__device__ __forceinline__ bf16x8 cvt8(f32x4 a, f32x4 b) {
    bf16x8 r;
    r[0] = (__bf16)a[0]; r[1] = (__bf16)a[1];
    r[2] = (__bf16)a[2]; r[3] = (__bf16)a[3];
    r[4] = (__bf16)b[0]; r[5] = (__bf16)b[1];
    r[6] = (__bf16)b[2]; r[7] = (__bf16)b[3];
    return r;
}

__device__ __forceinline__ void gll16(const void* g, void* l) {
    __builtin_amdgcn_global_load_lds(
        (const __attribute__((address_space(1))) void*)g,
        (__attribute__((address_space(3))) void*)l, 16, 0, 0);
}

__device__ __forceinline__ void ksplit(int s, int nsplit, int total,
                                       int& beg, int& cnt) {
    int q = total / nsplit, r = total % nsplit;
    cnt = q + (s < r ? 1 : 0);
    beg = s * q + (s < r ? s : r);
}

__global__ __launch_bounds__(256) void k_cvt_x(const float* __restrict__ x,
                                               __bf16* __restrict__ xb) {
    int i = (blockIdx.x * 256 + threadIdx.x) * 4;
    f32x4 v = *(const f32x4*)(x + i);
    xb[i + 0] = (__bf16)v[0]; xb[i + 1] = (__bf16)v[1];
    xb[i + 2] = (__bf16)v[2]; xb[i + 3] = (__bf16)v[3];
}

// R13 gate/up: pure-linear-sweep staging (the m13 copy pattern, verbatim).
// Block = ONE array x 16 consecutive W-rows x FULL K=4096. 8 waves; wave w
// sweeps rows {2w, 2w+1} entirely: per row 16 back-to-back dwordx4 (1 KB
// each) = 16 KB linearly contiguous; per wave 32 KB. Prune+cvt once, store
// bf16 into 128 KB dynamic-LDS tile (XOR-swizzled 16B slots). One barrier.
// Compute: wave = (token-group tg = wv>>2, k-chunk kc = wv&3), 32 MFMA
// steps over its 1024-float chunk; 4-way k-chunk reduce in LDS; output
// written ONCE (no split partials).
__global__ __launch_bounds__(512, 2) void k_gu(
        const float* __restrict__ GW, const float* __restrict__ UW,
        const __bf16* __restrict__ XB,
        float* __restrict__ gout, float* __restrict__ uout) {
    extern __shared__ __align__(16) char smem[];   // 128 KiB tile + 6 KiB part
    float* part = (float*)(smem + 16 * 8192);

    const int lane = threadIdx.x & 63;
    const int wv   = threadIdx.x >> 6;     // 0..7
    const int i0   = blockIdx.x * 16;      // 688 row-tiles
    const int arr  = blockIdx.y;           // 0=G, 1=U

    const float* WA = arr ? UW : GW;

    // ---- stage: 2 rows per wave, each a 16 KB LINEAR sweep
    #pragma unroll
    for (int rr = 0; rr < 2; ++rr) {
        const int rw = wv * 2 + rr;
        const float* rp = WA + (size_t)(i0 + rw) * H_DIM + lane * 4;
        char* rowb = smem + rw * 8192;
        const unsigned sw = (unsigned)((rw & 7) << 4);
        #pragma unroll
        for (int i = 0; i < 16; i += 4) {
            f32x4 v0 = *(const f32x4*)(rp + (i + 0) * 256);
            f32x4 v1 = *(const f32x4*)(rp + (i + 1) * 256);
            f32x4 v2 = *(const f32x4*)(rp + (i + 2) * 256);
            f32x4 v3 = *(const f32x4*)(rp + (i + 3) * 256);
            #pragma unroll
            for (int j = 0; j < 4; ++j) {
                f32x4 w = prune4(j == 0 ? v0 : j == 1 ? v1 : j == 2 ? v2 : v3);
                bf16x4 b;
                b[0] = (__bf16)w[0]; b[1] = (__bf16)w[1];
                b[2] = (__bf16)w[2]; b[3] = (__bf16)w[3];
                const unsigned off =
                    ((unsigned)((i + j) * 512 + lane * 8)) ^ sw;
                *(bf16x4*)(rowb + off) = b;
            }
        }
    }
    __syncthreads();

    // ---- compute: 32 MFMA k-steps over this wave's 1024-float chunk
    const int tg   = wv >> 2;              // token group (0/1)
    const int kc   = wv & 3;               // k chunk (0..3)
    const int lrow = lane & 15;
    const int hi   = lane >> 4;

    f32x4 acc = {0, 0, 0, 0};
    const __bf16* xbase = XB + (size_t)(tg * 16 + lrow) * H_DIM
                          + kc * 1024 + hi * 8;
    const char* rB = smem + lrow * 8192;
    const unsigned swr = (unsigned)((lrow & 7) << 4);
    #pragma unroll
    for (int s = 0; s < 32; ++s) {
        bf16x8 xa = *(const bf16x8*)(xbase + s * 32);
        const unsigned off =
            ((unsigned)(kc * 2048 + s * 64 + hi * 16)) ^ swr;
        bf16x8 bw = *(const bf16x8*)(rB + off);
        acc = __builtin_amdgcn_mfma_f32_16x16x32_bf16(xa, bw, acc, 0, 0, 0);
    }

    // ---- reduce k-chunks (kc 1..3 -> LDS, kc 0 accumulates + writes once)
    if (kc != 0)
        *(f32x4*)&part[((tg * 3) + (kc - 1)) * 256 + lane * 4] = acc;
    __syncthreads();
    if (kc == 0) {
        #pragma unroll
        for (int j = 0; j < 3; ++j)
            acc += *(const f32x4*)&part[((tg * 3) + j) * 256 + lane * 4];
        float* OUT = arr ? uout : gout;
        const int wcol = i0 + lrow;            // C/D: col=lane&15 = W-row
        const int trow = tg * 16 + hi * 4;     // token = (lane>>4)*4 + q
        #pragma unroll
        for (int q = 0; q < 4; ++q)
            OUT[(size_t)(trow + q) * I_DIM + wcol] = acc[q];
    }
}

__global__ __launch_bounds__(256) void k_hidden(
        const float* __restrict__ gpart, const float* __restrict__ upart,
        const float* __restrict__ gb, const float* __restrict__ ub,
        __bf16* __restrict__ hb, int nsplit) {
    const int i = blockIdx.x * 256 + threadIdx.x;  // 43*256 = 11008
    const int t = blockIdx.y;
    float g = gb[i], u = ub[i];
    for (int s = 0; s < nsplit; ++s) {
        g += gpart[(size_t)(s * 32 + t) * I_DIM + i];
        u += upart[(size_t)(s * 32 + t) * I_DIM + i];
    }
    float h = g / (1.0f + __expf(-g)) * u;   // silu(g)*u
    hb[(size_t)t * I_DIM + i] = (__bf16)h;
}

// down: R9-R12-passing dbuf + rotation version, unchanged.
__global__ __launch_bounds__(256) void k_down(
        const float* __restrict__ DW, const __bf16* __restrict__ HB,
        float* __restrict__ opart, int nsplit) {
    __shared__ __align__(16) float ldsd[2][32][BK];      // 32 KiB
    const int lane = threadIdx.x & 63;
    const int wv   = threadIdx.x >> 6;
    const int o0   = blockIdx.x * 32;      // 128 tiles
    int kbegstep, ksteps;
    ksplit(blockIdx.y, nsplit, KSTEPS_DN, kbegstep, ksteps);
    const int rot = (blockIdx.x * 7 + blockIdx.y) % ksteps;

    const int lrow = lane & 15;
    const int hi   = lane >> 4;
    const int rg0  = (wv & 1) * 16;
    const int t0   = (wv >> 1) * 16;
    const int r    = rg0 + lrow;
    const int sw   = r & 7;
    const int srow0 = (lane >> 5);

    f32x4 acc = {0,0,0,0};

    {
        const int kbeg = (kbegstep + rot) * BK;
        #pragma unroll
        for (int c = 0; c < 4; ++c) {
            const int pr  = wv * 4 + c;    // 0..15
            const int row = pr * 2 + srow0;
            const float* base = DW + (size_t)(o0 + row) * I_DIM + kbeg;
            gll16(base + (((lane & 31) ^ (row & 7)) << 2), &ldsd[0][pr * 2][0]);
        }
    }

    for (int m = 0; m < ksteps; ++m) {
        const int buf  = m & 1;
        int mm = m + rot; if (mm >= ksteps) mm -= ksteps;
        const int kbeg = (kbegstep + mm) * BK;
        __syncthreads();

        bf16x8 hf[4];
        const __bf16* hp = HB + (size_t)(t0 + lrow) * I_DIM + kbeg + hi * 8;
        #pragma unroll
        for (int ks = 0; ks < 4; ++ks) hf[ks] = *(const bf16x8*)(hp + ks * 32);

        if (m + 1 < ksteps) {
            int mn = m + 1 + rot; if (mn >= ksteps) mn -= ksteps;
            const int nkbeg = (kbegstep + mn) * BK;
            #pragma unroll
            for (int c = 0; c < 4; ++c) {
                const int pr  = wv * 4 + c;
                const int row = pr * 2 + srow0;
                const float* base = DW + (size_t)(o0 + row) * I_DIM + nkbeg;
                gll16(base + (((lane & 31) ^ (row & 7)) << 2),
                      &ldsd[buf ^ 1][pr * 2][0]);
            }
        }

        const char* dB = (const char*)&ldsd[buf][r][0];
        #pragma unroll
        for (int ks = 0; ks < 4; ++ks) {
            const int u0 = ks * 8 + hi * 2;
            f32x4 dl = *(const f32x4*)(dB + ((u0 ^ sw) << 4));
            f32x4 dh = *(const f32x4*)(dB + (((u0 + 1) ^ sw) << 4));
            bf16x8 bw = cvt8(dl, dh);
            acc = __builtin_amdgcn_mfma_f32_16x16x32_bf16(hf[ks], bw, acc, 0, 0, 0);
        }
    }

    const int wcol = o0 + rg0 + lrow;
    const int trow = t0 + hi * 4;
    const size_t srow = (size_t)blockIdx.y * 32;
    #pragma unroll
    for (int q = 0; q < 4; ++q)
        opart[(srow + trow + q) * H_DIM + wcol] = acc[q];
}

__global__ __launch_bounds__(256) void k_out(
        const float* __restrict__ opart, const float* __restrict__ db,
        float* __restrict__ out, int nsplit) {
    const int o = blockIdx.x * 256 + threadIdx.x;  // 16*256 = 4096
    const int t = blockIdx.y;
    float v = db[o];
    for (int s = 0; s < nsplit; ++s)
        v += opart[(size_t)(s * 32 + t) * H_DIM + o];
    out[(size_t)t * H_DIM + o] = v;
}

extern "C" void kernel_launch(void* const* d_in, const int* in_sizes, int n_in,
                              void* d_out, int out_size, void* d_ws, size_t ws_size,
                              hipStream_t stream) {
    const float* x  = (const float*)d_in[0];
    const float* gw = (const float*)d_in[1];
    const float* uw = (const float*)d_in[2];
    const float* dw = (const float*)d_in[3];
    const float* gb = (const float*)d_in[4];
    const float* ub = (const float*)d_in[5];
    const float* db = (const float*)d_in[6];
    float* out = (float*)d_out;

    const int ns2 = 8;
    const size_t XB_BYTES = (size_t)32 * H_DIM * 2;          // 256 KiB
    const size_t HB_BYTES = (size_t)32 * I_DIM * 2;          // 688 KiB
    const size_t GP_BYTES = (size_t)32 * I_DIM * 4;          // 1.41 MiB (single)
    char* ws = (char*)d_ws;
    __bf16* xb    = (__bf16*)(ws);
    __bf16* hb    = (__bf16*)(ws + XB_BYTES);
    float*  gpart = (float*)(ws + XB_BYTES + HB_BYTES);
    float*  upart = (float*)(ws + XB_BYTES + HB_BYTES + GP_BYTES);
    float*  opart = (float*)(ws + XB_BYTES + HB_BYTES + 2 * GP_BYTES);

    const size_t GU_LDS = 16 * 8192 + 6 * 1024;   // 134 KiB dynamic LDS

    k_cvt_x <<<dim3(128),              dim3(256), 0,      stream>>>(x, xb);
    k_gu    <<<dim3(I_DIM / 16, 2),    dim3(512), GU_LDS, stream>>>(gw, uw, xb, gpart, upart);
    k_hidden<<<dim3(I_DIM / 256, 32),  dim3(256), 0,      stream>>>(gpart, upart, gb, ub, hb, 1);
    k_down  <<<dim3(H_DIM / 32, ns2),  dim3(256), 0,      stream>>>(dw, hb, opart, ns2);
    k_out   <<<dim3(H_DIM / 256, 32),  dim3(256), 0,      stream>>>(opart, db, out, ns2);
}

// Round 14
// 138.176 us; speedup vs baseline: 1.2335x; 1.2335x over previous
//
#include <hip/hip_runtime.h>

typedef float f32x4 __attribute__((ext_vector_type(4)));
typedef __bf16 bf16x8 __attribute__((ext_vector_type(8)));
typedef __bf16 bf16x4 __attribute__((ext_vector_type(4)));

#define H_DIM 4096
#define I_DIM 11008
#define BK 128                    // down-kernel k floats per step
#define KSTEPS_DN (I_DIM / BK)    // 86

// 2:4 prune of one contiguous group of 4 (stable argsort tie semantics).
// FLOAT-COMPARE version (passed R1-R5/R9-R13). Integer-key variant is
// empirically broken on this platform -- do not resurrect.
__device__ __forceinline__ f32x4 prune4(f32x4 w) {
    float a0 = fabsf(w[0]), a1 = fabsf(w[1]), a2 = fabsf(w[2]), a3 = fabsf(w[3]);
    int r0 = (int)(a1 < a0) + (int)(a2 < a0) + (int)(a3 < a0);
    int r1 = (int)(a0 <= a1) + (int)(a2 < a1) + (int)(a3 < a1);
    int r2 = (int)(a0 <= a2) + (int)(a1 <= a2) + (int)(a3 < a2);
    int r3 = (int)(a0 <= a3) + (int)(a1 <= a3) + (int)(a2 <= a3);
    w[0] = (r0 >= 2) ? w[0] : 0.0f;
    w[1] = (r1 >= 2) ? w[1] : 0.0f;
    w[2] = (r2 >= 2) ? w[2] : 0.0f;
    w[3] = (r3 >= 2) ? w[3] : 0.0f;
    return w;
}

__device__ __forceinline__ bf16x8 cvt8(f32x4 a, f32x4 b) {
    bf16x8 r;
    r[0] = (__bf16)a[0]; r[1] = (__bf16)a[1];
    r[2] = (__bf16)a[2]; r[3] = (__bf16)a[3];
    r[4] = (__bf16)b[0]; r[5] = (__bf16)b[1];
    r[6] = (__bf16)b[2]; r[7] = (__bf16)b[3];
    return r;
}

__device__ __forceinline__ void gll16(const void* g, void* l) {
    __builtin_amdgcn_global_load_lds(
        (const __attribute__((address_space(1))) void*)g,
        (__attribute__((address_space(3))) void*)l, 16, 0, 0);
}

__device__ __forceinline__ void ksplit(int s, int nsplit, int total,
                                       int& beg, int& cnt) {
    int q = total / nsplit, r = total % nsplit;
    cnt = q + (s < r ? 1 : 0);
    beg = s * q + (s < r ? s : r);
}

__global__ __launch_bounds__(256) void k_cvt_x(const float* __restrict__ x,
                                               __bf16* __restrict__ xb) {
    int i = (blockIdx.x * 256 + threadIdx.x) * 4;
    f32x4 v = *(const f32x4*)(x + i);
    xb[i + 0] = (__bf16)v[0]; xb[i + 1] = (__bf16)v[1];
    xb[i + 2] = (__bf16)v[2]; xb[i + 3] = (__bf16)v[3];
}

// gate+up, register-staged long-burst version (best measured: 138.78 us).
// kwin = ((bx+by)&3)*1024 spreads co-resident blocks across k-windows.
__global__ __launch_bounds__(512, 4) void k_gateup(
        const float* __restrict__ GW, const float* __restrict__ UW,
        const __bf16* __restrict__ XB,
        float* __restrict__ gpart, float* __restrict__ upart) {
    __shared__ __align__(16) __bf16 bfw[2][16][1024];   // 64 KiB pruned bf16
    __shared__ __align__(16) float  part[6][64][8];     // 12 KiB k-partials

    const int lane = threadIdx.x & 63;
    const int wv   = threadIdx.x >> 6;     // 0..7
    const int i0   = blockIdx.x * 16;      // 688 row-tiles
    const int kwin = ((blockIdx.x + blockIdx.y) & 3) * 1024;  // channel-spread

    const int sarr = wv >> 2;              // staging: which array
    const int srow = (wv & 3) * 4;         // staging: base of 4 rows
    const int tg   = wv >> 2;              // compute: token group
    const int kq   = wv & 3;               // compute: k quarter
    const int lrow = lane & 15;
    const int hi   = lane >> 4;            // 0..3

    const float* WA = sarr ? UW : GW;

    // ---- stage: 2 shots x (4 rows x 2KB contiguous burst per row)
    #pragma unroll
    for (int h = 0; h < 2; ++h) {
        f32x4 v[4][2];
        #pragma unroll
        for (int rr = 0; rr < 4; ++rr) {
            const float* p = WA + (size_t)(i0 + srow + rr) * H_DIM + kwin
                             + h * 512 + lane * 4;
            v[rr][0] = *(const f32x4*)(p);          // floats [l*4, l*4+4)
            v[rr][1] = *(const f32x4*)(p + 256);    // next 1KB chunk, same row
        }
        #pragma unroll
        for (int rr = 0; rr < 4; ++rr) {
            const int row = srow + rr;
            const unsigned swz = (unsigned)((row & 7) << 4);
            char* rowb = (char*)&bfw[sarr][row][0];
            #pragma unroll
            for (int c = 0; c < 2; ++c) {
                f32x4 w = prune4(v[rr][c]);
                bf16x4 b;
                b[0] = (__bf16)w[0]; b[1] = (__bf16)w[1];
                b[2] = (__bf16)w[2]; b[3] = (__bf16)w[3];
                const unsigned off =
                    ((unsigned)(h * 1024 + c * 512 + lane * 8)) ^ swz;
                *(bf16x4*)(rowb + off) = b;
            }
        }
    }
    __syncthreads();

    // ---- compute: 8 MFMA k-steps over this wave's quarter
    f32x4 accG = {0,0,0,0}, accU = {0,0,0,0};
    const __bf16* xbase = XB + (size_t)(tg * 16 + lrow) * H_DIM
                          + kwin + kq * 256 + hi * 8;
    const unsigned swr = (unsigned)((lrow & 7) << 4);
    const char* gR = (const char*)&bfw[0][lrow][0];
    const char* uR = (const char*)&bfw[1][lrow][0];
    #pragma unroll
    for (int s = 0; s < 8; ++s) {
        bf16x8 xa = *(const bf16x8*)(xbase + s * 32);
        const unsigned off =
            ((unsigned)((kq * 256 + s * 32 + hi * 8) * 2)) ^ swr;
        bf16x8 bg = *(const bf16x8*)(gR + off);
        bf16x8 bu = *(const bf16x8*)(uR + off);
        accG = __builtin_amdgcn_mfma_f32_16x16x32_bf16(xa, bg, accG, 0, 0, 0);
        accU = __builtin_amdgcn_mfma_f32_16x16x32_bf16(xa, bu, accU, 0, 0, 0);
    }

    // ---- reduce k-quarters (kq 1..3 -> LDS, kq 0 accumulates + writes)
    if (kq != 0) {
        float* p = &part[tg * 3 + (kq - 1)][lane][0];
        *(f32x4*)p       = accG;
        *(f32x4*)(p + 4) = accU;
    }
    __syncthreads();
    if (kq == 0) {
        #pragma unroll
        for (int j = 0; j < 3; ++j) {
            const float* p = &part[tg * 3 + j][lane][0];
            accG += *(const f32x4*)p;
            accU += *(const f32x4*)(p + 4);
        }
        const int wcol = i0 + lrow;            // C/D: col=lane&15 = W-row
        const int trow = tg * 16 + hi * 4;     // token = (lane>>4)*4 + q
        const size_t so = (size_t)blockIdx.y * 32;
        #pragma unroll
        for (int q = 0; q < 4; ++q) {
            gpart[(so + trow + q) * I_DIM + wcol] = accG[q];
            upart[(so + trow + q) * I_DIM + wcol] = accU[q];
        }
    }
}

__global__ __launch_bounds__(256) void k_hidden(
        const float* __restrict__ gpart, const float* __restrict__ upart,
        const float* __restrict__ gb, const float* __restrict__ ub,
        __bf16* __restrict__ hb, int nsplit) {
    const int i = blockIdx.x * 256 + threadIdx.x;  // 43*256 = 11008
    const int t = blockIdx.y;
    float g = gb[i], u = ub[i];
    for (int s = 0; s < nsplit; ++s) {
        g += gpart[(size_t)(s * 32 + t) * I_DIM + i];
        u += upart[(size_t)(s * 32 + t) * I_DIM + i];
    }
    float h = g / (1.0f + __expf(-g)) * u;   // silu(g)*u
    hb[(size_t)t * I_DIM + i] = (__bf16)h;
}

// down: dbuf + rotation version (passing since R9), unchanged.
__global__ __launch_bounds__(256) void k_down(
        const float* __restrict__ DW, const __bf16* __restrict__ HB,
        float* __restrict__ opart, int nsplit) {
    __shared__ __align__(16) float ldsd[2][32][BK];      // 32 KiB
    const int lane = threadIdx.x & 63;
    const int wv   = threadIdx.x >> 6;
    const int o0   = blockIdx.x * 32;      // 128 tiles
    int kbegstep, ksteps;
    ksplit(blockIdx.y, nsplit, KSTEPS_DN, kbegstep, ksteps);
    const int rot = (blockIdx.x * 7 + blockIdx.y) % ksteps;

    const int lrow = lane & 15;
    const int hi   = lane >> 4;
    const int rg0  = (wv & 1) * 16;
    const int t0   = (wv >> 1) * 16;
    const int r    = rg0 + lrow;
    const int sw   = r & 7;
    const int srow0 = (lane >> 5);

    f32x4 acc = {0,0,0,0};

    {
        const int kbeg = (kbegstep + rot) * BK;
        #pragma unroll
        for (int c = 0; c < 4; ++c) {
            const int pr  = wv * 4 + c;    // 0..15
            const int row = pr * 2 + srow0;
            const float* base = DW + (size_t)(o0 + row) * I_DIM + kbeg;
            gll16(base + (((lane & 31) ^ (row & 7)) << 2), &ldsd[0][pr * 2][0]);
        }
    }

    for (int m = 0; m < ksteps; ++m) {
        const int buf  = m & 1;
        int mm = m + rot; if (mm >= ksteps) mm -= ksteps;
        const int kbeg = (kbegstep + mm) * BK;
        __syncthreads();

        bf16x8 hf[4];
        const __bf16* hp = HB + (size_t)(t0 + lrow) * I_DIM + kbeg + hi * 8;
        #pragma unroll
        for (int ks = 0; ks < 4; ++ks) hf[ks] = *(const bf16x8*)(hp + ks * 32);

        if (m + 1 < ksteps) {
            int mn = m + 1 + rot; if (mn >= ksteps) mn -= ksteps;
            const int nkbeg = (kbegstep + mn) * BK;
            #pragma unroll
            for (int c = 0; c < 4; ++c) {
                const int pr  = wv * 4 + c;
                const int row = pr * 2 + srow0;
                const float* base = DW + (size_t)(o0 + row) * I_DIM + nkbeg;
                gll16(base + (((lane & 31) ^ (row & 7)) << 2),
                      &ldsd[buf ^ 1][pr * 2][0]);
            }
        }

        const char* dB = (const char*)&ldsd[buf][r][0];
        #pragma unroll
        for (int ks = 0; ks < 4; ++ks) {
            const int u0 = ks * 8 + hi * 2;
            f32x4 dl = *(const f32x4*)(dB + ((u0 ^ sw) << 4));
            f32x4 dh = *(const f32x4*)(dB + (((u0 + 1) ^ sw) << 4));
            bf16x8 bw = cvt8(dl, dh);
            acc = __builtin_amdgcn_mfma_f32_16x16x32_bf16(hf[ks], bw, acc, 0, 0, 0);
        }
    }

    const int wcol = o0 + rg0 + lrow;
    const int trow = t0 + hi * 4;
    const size_t srow = (size_t)blockIdx.y * 32;
    #pragma unroll
    for (int q = 0; q < 4; ++q)
        opart[(srow + trow + q) * H_DIM + wcol] = acc[q];
}

__global__ __launch_bounds__(256) void k_out(
        const float* __restrict__ opart, const float* __restrict__ db,
        float* __restrict__ out, int nsplit) {
    const int o = blockIdx.x * 256 + threadIdx.x;  // 16*256 = 4096
    const int t = blockIdx.y;
    float v = db[o];
    for (int s = 0; s < nsplit; ++s)
        v += opart[(size_t)(s * 32 + t) * H_DIM + o];
    out[(size_t)t * H_DIM + o] = v;
}

extern "C" void kernel_launch(void* const* d_in, const int* in_sizes, int n_in,
                              void* d_out, int out_size, void* d_ws, size_t ws_size,
                              hipStream_t stream) {
    const float* x  = (const float*)d_in[0];
    const float* gw = (const float*)d_in[1];
    const float* uw = (const float*)d_in[2];
    const float* dw = (const float*)d_in[3];
    const float* gb = (const float*)d_in[4];
    const float* ub = (const float*)d_in[5];
    const float* db = (const float*)d_in[6];
    float* out = (float*)d_out;

    const int ns1 = 4, ns2 = 8;                              // proven footprint
    const size_t XB_BYTES = (size_t)32 * H_DIM * 2;          // 256 KiB
    const size_t HB_BYTES = (size_t)32 * I_DIM * 2;          // 688 KiB
    const size_t GP_UNIT  = (size_t)32 * I_DIM * 4;          // 1.38 MiB / split
    char* ws = (char*)d_ws;
    __bf16* xb    = (__bf16*)(ws);
    __bf16* hb    = (__bf16*)(ws + XB_BYTES);
    float*  gpart = (float*)(ws + XB_BYTES + HB_BYTES);
    float*  upart = (float*)(ws + XB_BYTES + HB_BYTES + GP_UNIT * ns1);
    float*  opart = (float*)(ws + XB_BYTES + HB_BYTES + 2 * GP_UNIT * ns1);

    k_cvt_x <<<dim3(128),                dim3(256), 0, stream>>>(x, xb);
    k_gateup<<<dim3(I_DIM / 16, ns1),    dim3(512), 0, stream>>>(gw, uw, xb, gpart, upart);
    k_hidden<<<dim3(I_DIM / 256, 32),    dim3(256), 0, stream>>>(gpart, upart, gb, ub, hb, ns1);
    k_down  <<<dim3(H_DIM / 32, ns2),    dim3(256), 0, stream>>>(dw, hb, opart, ns2);
    k_out   <<<dim3(H_DIM / 256, 32),    dim3(256), 0, stream>>>(opart, db, out, ns2);
}

// Round 15
// 126.324 us; speedup vs baseline: 1.3492x; 1.0938x over previous
//
#include <hip/hip_runtime.h>

typedef float f32x4 __attribute__((ext_vector_type(4)));
typedef __bf16 bf16x8 __attribute__((ext_vector_type(8)));
typedef __bf16 bf16x4 __attribute__((ext_vector_type(4)));

#define H_DIM 4096
#define I_DIM 11008
#define BK 128                    // down-kernel k floats per step
#define KSTEPS_DN (I_DIM / BK)    // 86

// 2:4 prune of one contiguous group of 4 (stable argsort tie semantics).
// FLOAT-COMPARE version (passed R1-R5/R9-R14). Integer-key variant is
// empirically broken on this platform -- do not resurrect.
__device__ __forceinline__ f32x4 prune4(f32x4 w) {
    float a0 = fabsf(w[0]), a1 = fabsf(w[1]), a2 = fabsf(w[2]), a3 = fabsf(w[3]);
    int r0 = (int)(a1 < a0) + (int)(a2 < a0) + (int)(a3 < a0);
    int r1 = (int)(a0 <= a1) + (int)(a2 < a1) + (int)(a3 < a1);
    int r2 = (int)(a0 <= a2) + (int)(a1 <= a2) + (int)(a3 < a2);
    int r3 = (int)(a0 <= a3) + (int)(a1 <= a3) + (int)(a2 <= a3);
    w[0] = (r0 >= 2) ? w[0] : 0.0f;
    w[1] = (r1 >= 2) ? w[1] : 0.0f;
    w[2] = (r2 >= 2) ? w[2] : 0.0f;
    w[3] = (r3 >= 2) ? w[3] : 0.0f;
    return w;
}

__device__ __forceinline__ bf16x8 cvt8(f32x4 a, f32x4 b) {
    bf16x8 r;
    r[0] = (__bf16)a[0]; r[1] = (__bf16)a[1];
    r[2] = (__bf16)a[2]; r[3] = (__bf16)a[3];
    r[4] = (__bf16)b[0]; r[5] = (__bf16)b[1];
    r[6] = (__bf16)b[2]; r[7] = (__bf16)b[3];
    return r;
}

__device__ __forceinline__ void gll16(const void* g, void* l) {
    __builtin_amdgcn_global_load_lds(
        (const __attribute__((address_space(1))) void*)g,
        (__attribute__((address_space(3))) void*)l, 16, 0, 0);
}

__device__ __forceinline__ void ksplit(int s, int nsplit, int total,
                                       int& beg, int& cnt) {
    int q = total / nsplit, r = total % nsplit;
    cnt = q + (s < r ? 1 : 0);
    beg = s * q + (s < r ? s : r);
}

__global__ __launch_bounds__(256) void k_cvt_x(const float* __restrict__ x,
                                               __bf16* __restrict__ xb) {
    int i = (blockIdx.x * 256 + threadIdx.x) * 4;
    f32x4 v = *(const f32x4*)(x + i);
    xb[i + 0] = (__bf16)v[0]; xb[i + 1] = (__bf16)v[1];
    xb[i + 2] = (__bf16)v[2]; xb[i + 3] = (__bf16)v[3];
}

// gate+up, register-staged long-burst version (R14 = 138.18 us baseline).
// R15 delta (ONE variable): weight loads are NON-TEMPORAL. Weights are
// single-touch (zero reuse) -- streaming 541 MB/call through the 256 MB L3
// forces a full-rate allocate/evict storm that may be the ~3 TB/s delivered
// wall. nt bypasses allocation: HBM serves the stream at pure-read rate and
// L3 is freed for genuinely-reused data (down_weight).
__global__ __launch_bounds__(512, 4) void k_gateup(
        const float* __restrict__ GW, const float* __restrict__ UW,
        const __bf16* __restrict__ XB,
        float* __restrict__ gpart, float* __restrict__ upart) {
    __shared__ __align__(16) __bf16 bfw[2][16][1024];   // 64 KiB pruned bf16
    __shared__ __align__(16) float  part[6][64][8];     // 12 KiB k-partials

    const int lane = threadIdx.x & 63;
    const int wv   = threadIdx.x >> 6;     // 0..7
    const int i0   = blockIdx.x * 16;      // 688 row-tiles
    const int kwin = ((blockIdx.x + blockIdx.y) & 3) * 1024;  // channel-spread

    const int sarr = wv >> 2;              // staging: which array
    const int srow = (wv & 3) * 4;         // staging: base of 4 rows
    const int tg   = wv >> 2;              // compute: token group
    const int kq   = wv & 3;               // compute: k quarter
    const int lrow = lane & 15;
    const int hi   = lane >> 4;            // 0..3

    const float* WA = sarr ? UW : GW;

    // ---- stage: 2 shots x (4 rows x 2KB contiguous burst per row)
    #pragma unroll
    for (int h = 0; h < 2; ++h) {
        f32x4 v[4][2];
        #pragma unroll
        for (int rr = 0; rr < 4; ++rr) {
            const float* p = WA + (size_t)(i0 + srow + rr) * H_DIM + kwin
                             + h * 512 + lane * 4;
            v[rr][0] = __builtin_nontemporal_load((const f32x4*)(p));
            v[rr][1] = __builtin_nontemporal_load((const f32x4*)(p + 256));
        }
        #pragma unroll
        for (int rr = 0; rr < 4; ++rr) {
            const int row = srow + rr;
            const unsigned swz = (unsigned)((row & 7) << 4);
            char* rowb = (char*)&bfw[sarr][row][0];
            #pragma unroll
            for (int c = 0; c < 2; ++c) {
                f32x4 w = prune4(v[rr][c]);
                bf16x4 b;
                b[0] = (__bf16)w[0]; b[1] = (__bf16)w[1];
                b[2] = (__bf16)w[2]; b[3] = (__bf16)w[3];
                const unsigned off =
                    ((unsigned)(h * 1024 + c * 512 + lane * 8)) ^ swz;
                *(bf16x4*)(rowb + off) = b;
            }
        }
    }
    __syncthreads();

    // ---- compute: 8 MFMA k-steps over this wave's quarter
    f32x4 accG = {0,0,0,0}, accU = {0,0,0,0};
    const __bf16* xbase = XB + (size_t)(tg * 16 + lrow) * H_DIM
                          + kwin + kq * 256 + hi * 8;
    const unsigned swr = (unsigned)((lrow & 7) << 4);
    const char* gR = (const char*)&bfw[0][lrow][0];
    const char* uR = (const char*)&bfw[1][lrow][0];
    #pragma unroll
    for (int s = 0; s < 8; ++s) {
        bf16x8 xa = *(const bf16x8*)(xbase + s * 32);
        const unsigned off =
            ((unsigned)((kq * 256 + s * 32 + hi * 8) * 2)) ^ swr;
        bf16x8 bg = *(const bf16x8*)(gR + off);
        bf16x8 bu = *(const bf16x8*)(uR + off);
        accG = __builtin_amdgcn_mfma_f32_16x16x32_bf16(xa, bg, accG, 0, 0, 0);
        accU = __builtin_amdgcn_mfma_f32_16x16x32_bf16(xa, bu, accU, 0, 0, 0);
    }

    // ---- reduce k-quarters (kq 1..3 -> LDS, kq 0 accumulates + writes)
    if (kq != 0) {
        float* p = &part[tg * 3 + (kq - 1)][lane][0];
        *(f32x4*)p       = accG;
        *(f32x4*)(p + 4) = accU;
    }
    __syncthreads();
    if (kq == 0) {
        #pragma unroll
        for (int j = 0; j < 3; ++j) {
            const float* p = &part[tg * 3 + j][lane][0];
            accG += *(const f32x4*)p;
            accU += *(const f32x4*)(p + 4);
        }
        const int wcol = i0 + lrow;            // C/D: col=lane&15 = W-row
        const int trow = tg * 16 + hi * 4;     // token = (lane>>4)*4 + q
        const size_t so = (size_t)blockIdx.y * 32;
        #pragma unroll
        for (int q = 0; q < 4; ++q) {
            gpart[(so + trow + q) * I_DIM + wcol] = accG[q];
            upart[(so + trow + q) * I_DIM + wcol] = accU[q];
        }
    }
}

__global__ __launch_bounds__(256) void k_hidden(
        const float* __restrict__ gpart, const float* __restrict__ upart,
        const float* __restrict__ gb, const float* __restrict__ ub,
        __bf16* __restrict__ hb, int nsplit) {
    const int i = blockIdx.x * 256 + threadIdx.x;  // 43*256 = 11008
    const int t = blockIdx.y;
    float g = gb[i], u = ub[i];
    for (int s = 0; s < nsplit; ++s) {
        g += gpart[(size_t)(s * 32 + t) * I_DIM + i];
        u += upart[(size_t)(s * 32 + t) * I_DIM + i];
    }
    float h = g / (1.0f + __expf(-g)) * u;   // silu(g)*u
    hb[(size_t)t * I_DIM + i] = (__bf16)h;
}

// down: dbuf + rotation version (passing since R9), unchanged.
__global__ __launch_bounds__(256) void k_down(
        const float* __restrict__ DW, const __bf16* __restrict__ HB,
        float* __restrict__ opart, int nsplit) {
    __shared__ __align__(16) float ldsd[2][32][BK];      // 32 KiB
    const int lane = threadIdx.x & 63;
    const int wv   = threadIdx.x >> 6;
    const int o0   = blockIdx.x * 32;      // 128 tiles
    int kbegstep, ksteps;
    ksplit(blockIdx.y, nsplit, KSTEPS_DN, kbegstep, ksteps);
    const int rot = (blockIdx.x * 7 + blockIdx.y) % ksteps;

    const int lrow = lane & 15;
    const int hi   = lane >> 4;
    const int rg0  = (wv & 1) * 16;
    const int t0   = (wv >> 1) * 16;
    const int r    = rg0 + lrow;
    const int sw   = r & 7;
    const int srow0 = (lane >> 5);

    f32x4 acc = {0,0,0,0};

    {
        const int kbeg = (kbegstep + rot) * BK;
        #pragma unroll
        for (int c = 0; c < 4; ++c) {
            const int pr  = wv * 4 + c;    // 0..15
            const int row = pr * 2 + srow0;
            const float* base = DW + (size_t)(o0 + row) * I_DIM + kbeg;
            gll16(base + (((lane & 31) ^ (row & 7)) << 2), &ldsd[0][pr * 2][0]);
        }
    }

    for (int m = 0; m < ksteps; ++m) {
        const int buf  = m & 1;
        int mm = m + rot; if (mm >= ksteps) mm -= ksteps;
        const int kbeg = (kbegstep + mm) * BK;
        __syncthreads();

        bf16x8 hf[4];
        const __bf16* hp = HB + (size_t)(t0 + lrow) * I_DIM + kbeg + hi * 8;
        #pragma unroll
        for (int ks = 0; ks < 4; ++ks) hf[ks] = *(const bf16x8*)(hp + ks * 32);

        if (m + 1 < ksteps) {
            int mn = m + 1 + rot; if (mn >= ksteps) mn -= ksteps;
            const int nkbeg = (kbegstep + mn) * BK;
            #pragma unroll
            for (int c = 0; c < 4; ++c) {
                const int pr  = wv * 4 + c;
                const int row = pr * 2 + srow0;
                const float* base = DW + (size_t)(o0 + row) * I_DIM + nkbeg;
                gll16(base + (((lane & 31) ^ (row & 7)) << 2),
                      &ldsd[buf ^ 1][pr * 2][0]);
            }
        }

        const char* dB = (const char*)&ldsd[buf][r][0];
        #pragma unroll
        for (int ks = 0; ks < 4; ++ks) {
            const int u0 = ks * 8 + hi * 2;
            f32x4 dl = *(const f32x4*)(dB + ((u0 ^ sw) << 4));
            f32x4 dh = *(const f32x4*)(dB + (((u0 + 1) ^ sw) << 4));
            bf16x8 bw = cvt8(dl, dh);
            acc = __builtin_amdgcn_mfma_f32_16x16x32_bf16(hf[ks], bw, acc, 0, 0, 0);
        }
    }

    const int wcol = o0 + rg0 + lrow;
    const int trow = t0 + hi * 4;
    const size_t srow = (size_t)blockIdx.y * 32;
    #pragma unroll
    for (int q = 0; q < 4; ++q)
        opart[(srow + trow + q) * H_DIM + wcol] = acc[q];
}

__global__ __launch_bounds__(256) void k_out(
        const float* __restrict__ opart, const float* __restrict__ db,
        float* __restrict__ out, int nsplit) {
    const int o = blockIdx.x * 256 + threadIdx.x;  // 16*256 = 4096
    const int t = blockIdx.y;
    float v = db[o];
    for (int s = 0; s < nsplit; ++s)
        v += opart[(size_t)(s * 32 + t) * H_DIM + o];
    out[(size_t)t * H_DIM + o] = v;
}

extern "C" void kernel_launch(void* const* d_in, const int* in_sizes, int n_in,
                              void* d_out, int out_size, void* d_ws, size_t ws_size,
                              hipStream_t stream) {
    const float* x  = (const float*)d_in[0];
    const float* gw = (const float*)d_in[1];
    const float* uw = (const float*)d_in[2];
    const float* dw = (const float*)d_in[3];
    const float* gb = (const float*)d_in[4];
    const float* ub = (const float*)d_in[5];
    const float* db = (const float*)d_in[6];
    float* out = (float*)d_out;

    const int ns1 = 4, ns2 = 8;                              // proven footprint
    const size_t XB_BYTES = (size_t)32 * H_DIM * 2;          // 256 KiB
    const size_t HB_BYTES = (size_t)32 * I_DIM * 2;          // 688 KiB
    const size_t GP_UNIT  = (size_t)32 * I_DIM * 4;          // 1.38 MiB / split
    char* ws = (char*)d_ws;
    __bf16* xb    = (__bf16*)(ws);
    __bf16* hb    = (__bf16*)(ws + XB_BYTES);
    float*  gpart = (float*)(ws + XB_BYTES + HB_BYTES);
    float*  upart = (float*)(ws + XB_BYTES + HB_BYTES + GP_UNIT * ns1);
    float*  opart = (float*)(ws + XB_BYTES + HB_BYTES + 2 * GP_UNIT * ns1);

    k_cvt_x <<<dim3(128),                dim3(256), 0, stream>>>(x, xb);
    k_gateup<<<dim3(I_DIM / 16, ns1),    dim3(512), 0, stream>>>(gw, uw, xb, gpart, upart);
    k_hidden<<<dim3(I_DIM / 256, 32),    dim3(256), 0, stream>>>(gpart, upart, gb, ub, hb, ns1);
    k_down  <<<dim3(H_DIM / 32, ns2),    dim3(256), 0, stream>>>(dw, hb, opart, ns2);
    k_out   <<<dim3(H_DIM / 256, 32),    dim3(256), 0, stream>>>(opart, db, out, ns2);
}

// Round 16
// 122.621 us; speedup vs baseline: 1.3899x; 1.0302x over previous
//
#include <hip/hip_runtime.h>

typedef float f32x4 __attribute__((ext_vector_type(4)));
typedef __bf16 bf16x8 __attribute__((ext_vector_type(8)));
typedef __bf16 bf16x4 __attribute__((ext_vector_type(4)));

#define H_DIM 4096
#define I_DIM 11008
#define BK 128                    // down-kernel k floats per step
#define KSTEPS_DN (I_DIM / BK)    // 86

// 2:4 prune of one contiguous group of 4 (stable argsort tie semantics).
// FLOAT-COMPARE version (passed R1-R5/R9-R15). Integer-key variant is
// empirically broken on this platform -- do not resurrect.
__device__ __forceinline__ f32x4 prune4(f32x4 w) {
    float a0 = fabsf(w[0]), a1 = fabsf(w[1]), a2 = fabsf(w[2]), a3 = fabsf(w[3]);
    int r0 = (int)(a1 < a0) + (int)(a2 < a0) + (int)(a3 < a0);
    int r1 = (int)(a0 <= a1) + (int)(a2 < a1) + (int)(a3 < a1);
    int r2 = (int)(a0 <= a2) + (int)(a1 <= a2) + (int)(a3 < a2);
    int r3 = (int)(a0 <= a3) + (int)(a1 <= a3) + (int)(a2 <= a3);
    w[0] = (r0 >= 2) ? w[0] : 0.0f;
    w[1] = (r1 >= 2) ? w[1] : 0.0f;
    w[2] = (r2 >= 2) ? w[2] : 0.0f;
    w[3] = (r3 >= 2) ? w[3] : 0.0f;
    return w;
}

__device__ __forceinline__ bf16x8 cvt8(f32x4 a, f32x4 b) {
    bf16x8 r;
    r[0] = (__bf16)a[0]; r[1] = (__bf16)a[1];
    r[2] = (__bf16)a[2]; r[3] = (__bf16)a[3];
    r[4] = (__bf16)b[0]; r[5] = (__bf16)b[1];
    r[6] = (__bf16)b[2]; r[7] = (__bf16)b[3];
    return r;
}

__device__ __forceinline__ void gll16(const void* g, void* l) {
    __builtin_amdgcn_global_load_lds(
        (const __attribute__((address_space(1))) void*)g,
        (__attribute__((address_space(3))) void*)l, 16, 0, 0);
}

__device__ __forceinline__ void ksplit(int s, int nsplit, int total,
                                       int& beg, int& cnt) {
    int q = total / nsplit, r = total % nsplit;
    cnt = q + (s < r ? 1 : 0);
    beg = s * q + (s < r ? s : r);
}

__global__ __launch_bounds__(256) void k_cvt_x(const float* __restrict__ x,
                                               __bf16* __restrict__ xb) {
    int i = (blockIdx.x * 256 + threadIdx.x) * 4;
    f32x4 v = *(const f32x4*)(x + i);
    xb[i + 0] = (__bf16)v[0]; xb[i + 1] = (__bf16)v[1];
    xb[i + 2] = (__bf16)v[2]; xb[i + 3] = (__bf16)v[3];
}

// gate+up, register-staged, NON-TEMPORAL weight loads (R15 = 126.3 us).
// R16 delta (ONE variable): stage issues ALL 16 dwordx4 back-to-back
// (full 4KB window of the wave's 4 rows) before any prune/cvt -- doubles
// per-wave in-flight bytes (8KB -> 16KB) and removes the mid-stage
// dependency stall. Layout, schedule, math byte-identical otherwise.
__global__ __launch_bounds__(512, 4) void k_gateup(
        const float* __restrict__ GW, const float* __restrict__ UW,
        const __bf16* __restrict__ XB,
        float* __restrict__ gpart, float* __restrict__ upart) {
    __shared__ __align__(16) __bf16 bfw[2][16][1024];   // 64 KiB pruned bf16
    __shared__ __align__(16) float  part[6][64][8];     // 12 KiB k-partials

    const int lane = threadIdx.x & 63;
    const int wv   = threadIdx.x >> 6;     // 0..7
    const int i0   = blockIdx.x * 16;      // 688 row-tiles
    const int kwin = ((blockIdx.x + blockIdx.y) & 3) * 1024;  // channel-spread

    const int sarr = wv >> 2;              // staging: which array
    const int srow = (wv & 3) * 4;         // staging: base of 4 rows
    const int tg   = wv >> 2;              // compute: token group
    const int kq   = wv & 3;               // compute: k quarter
    const int lrow = lane & 15;
    const int hi   = lane >> 4;            // 0..3

    const float* WA = sarr ? UW : GW;

    // ---- stage: issue ALL loads first (4 rows x 4KB, 16 dwordx4, nt),
    //      then prune+cvt+ds_write everything.
    f32x4 v[4][4];
    #pragma unroll
    for (int rr = 0; rr < 4; ++rr) {
        const float* p = WA + (size_t)(i0 + srow + rr) * H_DIM + kwin
                         + lane * 4;
        v[rr][0] = __builtin_nontemporal_load((const f32x4*)(p));
        v[rr][1] = __builtin_nontemporal_load((const f32x4*)(p + 256));
        v[rr][2] = __builtin_nontemporal_load((const f32x4*)(p + 512));
        v[rr][3] = __builtin_nontemporal_load((const f32x4*)(p + 768));
    }
    #pragma unroll
    for (int rr = 0; rr < 4; ++rr) {
        const int row = srow + rr;
        const unsigned swz = (unsigned)((row & 7) << 4);
        char* rowb = (char*)&bfw[sarr][row][0];
        #pragma unroll
        for (int c = 0; c < 4; ++c) {
            f32x4 w = prune4(v[rr][c]);
            bf16x4 b;
            b[0] = (__bf16)w[0]; b[1] = (__bf16)w[1];
            b[2] = (__bf16)w[2]; b[3] = (__bf16)w[3];
            const unsigned off =
                ((unsigned)(c * 512 + lane * 8)) ^ swz;
            *(bf16x4*)(rowb + off) = b;
        }
    }
    __syncthreads();

    // ---- compute: 8 MFMA k-steps over this wave's quarter
    f32x4 accG = {0,0,0,0}, accU = {0,0,0,0};
    const __bf16* xbase = XB + (size_t)(tg * 16 + lrow) * H_DIM
                          + kwin + kq * 256 + hi * 8;
    const unsigned swr = (unsigned)((lrow & 7) << 4);
    const char* gR = (const char*)&bfw[0][lrow][0];
    const char* uR = (const char*)&bfw[1][lrow][0];
    #pragma unroll
    for (int s = 0; s < 8; ++s) {
        bf16x8 xa = *(const bf16x8*)(xbase + s * 32);
        const unsigned off =
            ((unsigned)((kq * 256 + s * 32 + hi * 8) * 2)) ^ swr;
        bf16x8 bg = *(const bf16x8*)(gR + off);
        bf16x8 bu = *(const bf16x8*)(uR + off);
        accG = __builtin_amdgcn_mfma_f32_16x16x32_bf16(xa, bg, accG, 0, 0, 0);
        accU = __builtin_amdgcn_mfma_f32_16x16x32_bf16(xa, bu, accU, 0, 0, 0);
    }

    // ---- reduce k-quarters (kq 1..3 -> LDS, kq 0 accumulates + writes)
    if (kq != 0) {
        float* p = &part[tg * 3 + (kq - 1)][lane][0];
        *(f32x4*)p       = accG;
        *(f32x4*)(p + 4) = accU;
    }
    __syncthreads();
    if (kq == 0) {
        #pragma unroll
        for (int j = 0; j < 3; ++j) {
            const float* p = &part[tg * 3 + j][lane][0];
            accG += *(const f32x4*)p;
            accU += *(const f32x4*)(p + 4);
        }
        const int wcol = i0 + lrow;            // C/D: col=lane&15 = W-row
        const int trow = tg * 16 + hi * 4;     // token = (lane>>4)*4 + q
        const size_t so = (size_t)blockIdx.y * 32;
        #pragma unroll
        for (int q = 0; q < 4; ++q) {
            gpart[(so + trow + q) * I_DIM + wcol] = accG[q];
            upart[(so + trow + q) * I_DIM + wcol] = accU[q];
        }
    }
}

__global__ __launch_bounds__(256) void k_hidden(
        const float* __restrict__ gpart, const float* __restrict__ upart,
        const float* __restrict__ gb, const float* __restrict__ ub,
        __bf16* __restrict__ hb, int nsplit) {
    const int i = blockIdx.x * 256 + threadIdx.x;  // 43*256 = 11008
    const int t = blockIdx.y;
    float g = gb[i], u = ub[i];
    for (int s = 0; s < nsplit; ++s) {
        g += gpart[(size_t)(s * 32 + t) * I_DIM + i];
        u += upart[(size_t)(s * 32 + t) * I_DIM + i];
    }
    float h = g / (1.0f + __expf(-g)) * u;   // silu(g)*u
    hb[(size_t)t * I_DIM + i] = (__bf16)h;
}

// down: dbuf + rotation version (passing since R9), unchanged. DW stays
// CACHED (no nt): with gate/up streams bypassing L3, its 172 MB can remain
// L3-resident across replays.
__global__ __launch_bounds__(256) void k_down(
        const float* __restrict__ DW, const __bf16* __restrict__ HB,
        float* __restrict__ opart, int nsplit) {
    __shared__ __align__(16) float ldsd[2][32][BK];      // 32 KiB
    const int lane = threadIdx.x & 63;
    const int wv   = threadIdx.x >> 6;
    const int o0   = blockIdx.x * 32;      // 128 tiles
    int kbegstep, ksteps;
    ksplit(blockIdx.y, nsplit, KSTEPS_DN, kbegstep, ksteps);
    const int rot = (blockIdx.x * 7 + blockIdx.y) % ksteps;

    const int lrow = lane & 15;
    const int hi   = lane >> 4;
    const int rg0  = (wv & 1) * 16;
    const int t0   = (wv >> 1) * 16;
    const int r    = rg0 + lrow;
    const int sw   = r & 7;
    const int srow0 = (lane >> 5);

    f32x4 acc = {0,0,0,0};

    {
        const int kbeg = (kbegstep + rot) * BK;
        #pragma unroll
        for (int c = 0; c < 4; ++c) {
            const int pr  = wv * 4 + c;    // 0..15
            const int row = pr * 2 + srow0;
            const float* base = DW + (size_t)(o0 + row) * I_DIM + kbeg;
            gll16(base + (((lane & 31) ^ (row & 7)) << 2), &ldsd[0][pr * 2][0]);
        }
    }

    for (int m = 0; m < ksteps; ++m) {
        const int buf  = m & 1;
        int mm = m + rot; if (mm >= ksteps) mm -= ksteps;
        const int kbeg = (kbegstep + mm) * BK;
        __syncthreads();

        bf16x8 hf[4];
        const __bf16* hp = HB + (size_t)(t0 + lrow) * I_DIM + kbeg + hi * 8;
        #pragma unroll
        for (int ks = 0; ks < 4; ++ks) hf[ks] = *(const bf16x8*)(hp + ks * 32);

        if (m + 1 < ksteps) {
            int mn = m + 1 + rot; if (mn >= ksteps) mn -= ksteps;
            const int nkbeg = (kbegstep + mn) * BK;
            #pragma unroll
            for (int c = 0; c < 4; ++c) {
                const int pr  = wv * 4 + c;
                const int row = pr * 2 + srow0;
                const float* base = DW + (size_t)(o0 + row) * I_DIM + nkbeg;
                gll16(base + (((lane & 31) ^ (row & 7)) << 2),
                      &ldsd[buf ^ 1][pr * 2][0]);
            }
        }

        const char* dB = (const char*)&ldsd[buf][r][0];
        #pragma unroll
        for (int ks = 0; ks < 4; ++ks) {
            const int u0 = ks * 8 + hi * 2;
            f32x4 dl = *(const f32x4*)(dB + ((u0 ^ sw) << 4));
            f32x4 dh = *(const f32x4*)(dB + (((u0 + 1) ^ sw) << 4));
            bf16x8 bw = cvt8(dl, dh);
            acc = __builtin_amdgcn_mfma_f32_16x16x32_bf16(hf[ks], bw, acc, 0, 0, 0);
        }
    }

    const int wcol = o0 + rg0 + lrow;
    const int trow = t0 + hi * 4;
    const size_t srow = (size_t)blockIdx.y * 32;
    #pragma unroll
    for (int q = 0; q < 4; ++q)
        opart[(srow + trow + q) * H_DIM + wcol] = acc[q];
}

__global__ __launch_bounds__(256) void k_out(
        const float* __restrict__ opart, const float* __restrict__ db,
        float* __restrict__ out, int nsplit) {
    const int o = blockIdx.x * 256 + threadIdx.x;  // 16*256 = 4096
    const int t = blockIdx.y;
    float v = db[o];
    for (int s = 0; s < nsplit; ++s)
        v += opart[(size_t)(s * 32 + t) * H_DIM + o];
    out[(size_t)t * H_DIM + o] = v;
}

extern "C" void kernel_launch(void* const* d_in, const int* in_sizes, int n_in,
                              void* d_out, int out_size, void* d_ws, size_t ws_size,
                              hipStream_t stream) {
    const float* x  = (const float*)d_in[0];
    const float* gw = (const float*)d_in[1];
    const float* uw = (const float*)d_in[2];
    const float* dw = (const float*)d_in[3];
    const float* gb = (const float*)d_in[4];
    const float* ub = (const float*)d_in[5];
    const float* db = (const float*)d_in[6];
    float* out = (float*)d_out;

    const int ns1 = 4, ns2 = 8;                              // proven footprint
    const size_t XB_BYTES = (size_t)32 * H_DIM * 2;          // 256 KiB
    const size_t HB_BYTES = (size_t)32 * I_DIM * 2;          // 688 KiB
    const size_t GP_UNIT  = (size_t)32 * I_DIM * 4;          // 1.38 MiB / split
    char* ws = (char*)d_ws;
    __bf16* xb    = (__bf16*)(ws);
    __bf16* hb    = (__bf16*)(ws + XB_BYTES);
    float*  gpart = (float*)(ws + XB_BYTES + HB_BYTES);
    float*  upart = (float*)(ws + XB_BYTES + HB_BYTES + GP_UNIT * ns1);
    float*  opart = (float*)(ws + XB_BYTES + HB_BYTES + 2 * GP_UNIT * ns1);

    k_cvt_x <<<dim3(128),                dim3(256), 0, stream>>>(x, xb);
    k_gateup<<<dim3(I_DIM / 16, ns1),    dim3(512), 0, stream>>>(gw, uw, xb, gpart, upart);
    k_hidden<<<dim3(I_DIM / 256, 32),    dim3(256), 0, stream>>>(gpart, upart, gb, ub, hb, ns1);
    k_down  <<<dim3(H_DIM / 32, ns2),    dim3(256), 0, stream>>>(dw, hb, opart, ns2);
    k_out   <<<dim3(H_DIM / 256, 32),    dim3(256), 0, stream>>>(opart, db, out, ns2);
}